// Round 4
// baseline (83.911 us; speedup 1.0000x reference)
//
#include <hip/hip_runtime.h>
#include <hip/hip_bf16.h>

// Reference: C[bs*Q, bs*T] cross-batch cost matrix, [9600, 1600].
// Inputs f32 (setup_inputs -> jax f32 defaults), OUTPUT f32 (reference computes
// and returns f32; round-3 shuffle-signature confirmed the harness reads f32).
#define NROWS 9600
#define NCOLS 1600
#define COLS_PER_THREAD 4
#define THREADS 256
#define COLS_PER_BLOCK (THREADS * COLS_PER_THREAD)  // 1024
#define GRID_X 2                         // ceil(1600/1024)
#define ROWS_PER_BLOCK 16
#define GRID_Y (NROWS / ROWS_PER_BLOCK)  // 600

__global__ __launch_bounds__(THREADS)
void matcher_cost_kernel(const float* __restrict__ pred,  // [9600,4] f32 xyxy
                         const float* __restrict__ tgt,   // [1600,4] f32 xyxy
                         float* __restrict__ out)         // [9600,1600] f32
{
    const int c0 = blockIdx.x * COLS_PER_BLOCK + threadIdx.x * COLS_PER_THREAD;
    if (c0 >= NCOLS) return;  // whole thread in or out (NCOLS % 4 == 0)

    // Target columns: register-resident across all of this block's rows.
    float tx0[COLS_PER_THREAD], ty0[COLS_PER_THREAD], tx1[COLS_PER_THREAD],
          ty1[COLS_PER_THREAD], tw[COLS_PER_THREAD], th[COLS_PER_THREAD],
          ta4[COLS_PER_THREAD];
#pragma unroll
    for (int j = 0; j < COLS_PER_THREAD; ++j) {
        const float4 t = *reinterpret_cast<const float4*>(tgt + (c0 + j) * 4);
        tx0[j] = t.x; ty0[j] = t.y; tx1[j] = t.z; ty1[j] = t.w;
        tw[j] = t.z - t.x;                   // target width  (>=0 by construction)
        th[j] = t.w - t.y;                   // target height
        ta4[j] = 4.0f * tw[j] * th[j];       // 4 * area2
    }

    const int row0 = blockIdx.y * ROWS_PER_BLOCK;
    float* __restrict__ obase = out + (size_t)row0 * NCOLS + c0;

    for (int r = 0; r < ROWS_PER_BLOCK; ++r) {
        // Wave-uniform pred row -> compiler emits scalar loads (free pipe).
        const float4 q = *reinterpret_cast<const float4*>(pred + (row0 + r) * 4);
        const float qw = q.z - q.x;
        const float qh = q.w - q.y;
        const float qa4 = 4.0f * qw * qh;    // 4 * area1

        float c[COLS_PER_THREAD];
#pragma unroll
        for (int j = 0; j < COLS_PER_THREAD; ++j) {
            // coordinate deltas; abs() is a free VALU input modifier
            const float d0 = q.x - tx0[j];
            const float d1 = q.y - ty0[j];
            const float d2 = q.z - tx1[j];
            const float d3 = q.w - ty1[j];
            const float cbx = fabsf(d0) + fabsf(d2);
            const float cby = fabsf(d1) + fabsf(d3);
            const float cb  = cbx + cby;     // L1 (cost_bbox)

            // min/max identity: 2*iw = (qw+tw) - (|d0|+|d2|); 2*ew = (qw+tw) + (|d0|+|d2|)
            const float wx = qw + tw[j];
            const float wy = qh + th[j];
            const float iw = fmaxf(wx - cbx, 0.0f);
            const float ih = fmaxf(wy - cby, 0.0f);
            const float ew = wx + cbx;       // >= 0 always
            const float eh = wy + cby;

            const float I4 = iw * ih;                 // 4 * inter
            const float E4 = ew * eh;                 // 4 * enclose
            const float U4 = (qa4 + ta4[j]) - I4;     // 4 * union

            // giou = I/U - (E-U)/E = (I4*E4 + U4*(U4-E4)) / (U4*E4); scale cancels.
            // U4==0 (both boxes degenerate) => num=0, den=0 => NaN, matching ref's 0/0.
            const float num = fmaf(U4, U4 - E4, I4 * E4);
            const float den = U4 * E4;
            float C = fmaf(-num, __builtin_amdgcn_rcpf(den), cb);  // cb - giou
            // (clamp(giou,-1,1) is a no-op: |giou| <= 1 analytically for valid boxes)
            c[j] = (C != C) ? 1e5f : C;      // NaN sanitization (jnp.where(isnan))
        }
        // 16B per lane, lane-consecutive -> perfectly coalesced dwordx4 store.
        *reinterpret_cast<float4*>(obase) = make_float4(c[0], c[1], c[2], c[3]);
        obase += NCOLS;
    }
}

extern "C" void kernel_launch(void* const* d_in, const int* in_sizes, int n_in,
                              void* d_out, int out_size, void* d_ws, size_t ws_size,
                              hipStream_t stream) {
    const float* pred = (const float*)d_in[0];   // pred_boxes [32,300,4] f32
    const float* tgt  = (const float*)d_in[1];   // boxes      [32,50,4]  f32
    float* out = (float*)d_out;                  // [32,300,1600] f32
    dim3 grid(GRID_X, GRID_Y);
    matcher_cost_kernel<<<grid, THREADS, 0, stream>>>(pred, tgt, out);
}

// Round 6
// 81.974 us; speedup vs baseline: 1.0236x; 1.0236x over previous
//
#include <hip/hip_runtime.h>
#include <hip/hip_bf16.h>

// Reference: C[bs*Q, bs*T] cross-batch cost matrix, [9600, 1600]. f32 in, f32 out.
// R4 passed (absmax 0.0156, dur_us 83.9). Kernel is store-bound: floor =
// 61.44MB / 6.03TB/s (measured fill BW) = 10.2us; dur_us is dominated by the
// harness poison fills (44.5us ws + ~10us out, measured in R4 counters).
// This round: tail-quantization fix (2400 blocks, 9.4/CU) + nontemporal stores
// (via native clang vector type -- HIP float4 is rejected by the builtin).
#define NROWS 9600
#define NCOLS 1600
#define COLS_PER_THREAD 4
#define THREADS 256
#define COLS_PER_BLOCK (THREADS * COLS_PER_THREAD)  // 1024
#define GRID_X 2                         // ceil(1600/1024)
#define ROWS_PER_BLOCK 8
#define GRID_Y (NROWS / ROWS_PER_BLOCK)  // 1200

typedef float vfloat4 __attribute__((ext_vector_type(4)));  // native vector for nt-store

__global__ __launch_bounds__(THREADS)
void matcher_cost_kernel(const float* __restrict__ pred,  // [9600,4] f32 xyxy
                         const float* __restrict__ tgt,   // [1600,4] f32 xyxy
                         float* __restrict__ out)         // [9600,1600] f32
{
    const int c0 = blockIdx.x * COLS_PER_BLOCK + threadIdx.x * COLS_PER_THREAD;
    if (c0 >= NCOLS) return;  // whole thread in or out (NCOLS % 4 == 0)

    // Target columns: register-resident across all of this block's rows.
    float tx0[COLS_PER_THREAD], ty0[COLS_PER_THREAD], tx1[COLS_PER_THREAD],
          ty1[COLS_PER_THREAD], tw[COLS_PER_THREAD], th[COLS_PER_THREAD],
          ta4[COLS_PER_THREAD];
#pragma unroll
    for (int j = 0; j < COLS_PER_THREAD; ++j) {
        const float4 t = *reinterpret_cast<const float4*>(tgt + (c0 + j) * 4);
        tx0[j] = t.x; ty0[j] = t.y; tx1[j] = t.z; ty1[j] = t.w;
        tw[j] = t.z - t.x;                   // target width  (>=0 by construction)
        th[j] = t.w - t.y;                   // target height
        ta4[j] = 4.0f * tw[j] * th[j];       // 4 * area2
    }

    const int row0 = blockIdx.y * ROWS_PER_BLOCK;
    float* __restrict__ obase = out + (size_t)row0 * NCOLS + c0;

#pragma unroll
    for (int r = 0; r < ROWS_PER_BLOCK; ++r) {
        // Wave-uniform pred row -> scalar load path (free pipe).
        const float4 q = *reinterpret_cast<const float4*>(pred + (row0 + r) * 4);
        const float qw = q.z - q.x;
        const float qh = q.w - q.y;
        const float qa4 = 4.0f * qw * qh;    // 4 * area1

        float c[COLS_PER_THREAD];
#pragma unroll
        for (int j = 0; j < COLS_PER_THREAD; ++j) {
            // coordinate deltas; abs() is a free VALU input modifier
            const float d0 = q.x - tx0[j];
            const float d1 = q.y - ty0[j];
            const float d2 = q.z - tx1[j];
            const float d3 = q.w - ty1[j];
            const float cbx = fabsf(d0) + fabsf(d2);
            const float cby = fabsf(d1) + fabsf(d3);
            const float cb  = cbx + cby;     // L1 (cost_bbox)

            // min/max identity: 2*iw = (qw+tw) - (|d0|+|d2|); 2*ew = (qw+tw) + (|d0|+|d2|)
            const float wx = qw + tw[j];
            const float wy = qh + th[j];
            const float iw = fmaxf(wx - cbx, 0.0f);
            const float ih = fmaxf(wy - cby, 0.0f);
            const float ew = wx + cbx;       // >= 0 always
            const float eh = wy + cby;

            const float I4 = iw * ih;                 // 4 * inter
            const float E4 = ew * eh;                 // 4 * enclose
            const float U4 = (qa4 + ta4[j]) - I4;     // 4 * union

            // giou = I/U - (E-U)/E = (I4*E4 + U4*(U4-E4)) / (U4*E4); scale cancels.
            // U4==0 (both boxes degenerate) => 0/0 => NaN, matching the reference.
            const float num = fmaf(U4, U4 - E4, I4 * E4);
            const float den = U4 * E4;
            float C = fmaf(-num, __builtin_amdgcn_rcpf(den), cb);  // cb - giou
            c[j] = (C != C) ? 1e5f : C;      // NaN sanitization (jnp.where(isnan))
        }
        // 16B per lane, lane-consecutive, write-once -> nontemporal dwordx4 store.
        vfloat4 v; v.x = c[0]; v.y = c[1]; v.z = c[2]; v.w = c[3];
        __builtin_nontemporal_store(v, reinterpret_cast<vfloat4*>(obase));
        obase += NCOLS;
    }
}

extern "C" void kernel_launch(void* const* d_in, const int* in_sizes, int n_in,
                              void* d_out, int out_size, void* d_ws, size_t ws_size,
                              hipStream_t stream) {
    const float* pred = (const float*)d_in[0];   // pred_boxes [32,300,4] f32
    const float* tgt  = (const float*)d_in[1];   // boxes      [32,50,4]  f32
    float* out = (float*)d_out;                  // [32,300,1600] f32
    dim3 grid(GRID_X, GRID_Y);
    matcher_cost_kernel<<<grid, THREADS, 0, stream>>>(pred, tgt, out);
}